// Round 3
// baseline (534.621 us; speedup 1.0000x reference)
//
#include <hip/hip_runtime.h>
#include <math.h>

typedef unsigned long long u64;
typedef unsigned int u32;

#define NB 16
#define SL 1024
#define DIM 16
#define MDIM 16
#define KNN 8
#define EH 66    /* edge hidden */
#define CH 64    /* coors hidden */
#define NHID 32  /* node hidden */
#define LN_EPS 1e-5f
#define W1T_STRIDE 36   /* 33 padded to 16B multiple */

__device__ __forceinline__ float silu_f(float x) {
    return x / (1.0f + __expf(-x));
}

// ---------------- init ----------------
__global__ __launch_bounds__(256) void init_kernel(
    const float* __restrict__ coords, const int* __restrict__ residues,
    const float* __restrict__ token_emb, const float* __restrict__ pos_emb,
    float* __restrict__ coordsA, float* __restrict__ featsA)
{
    const int nid = blockIdx.x * 256 + threadIdx.x;
    if (nid >= NB * SL) return;
    const int l = nid & (SL - 1);
    const int r = residues[nid];
#pragma unroll
    for (int c = 0; c < DIM; ++c)
        featsA[nid * DIM + c] = token_emb[r * DIM + c] + pos_emb[l * DIM + c];
#pragma unroll
    for (int c = 0; c < 3; ++c)
        coordsA[nid * 3 + c] = coords[nid * 3 + c];
}

// ---------------- weight transpose/pack ----------------
__global__ __launch_bounds__(256) void pack_kernel(
    const float* __restrict__ ew1, const float* __restrict__ cw1,
    const float* __restrict__ nw1, const float* __restrict__ nw2,
    float* __restrict__ w1t, float* __restrict__ cw1t,
    float* __restrict__ nw1t, float* __restrict__ nw2t)
{
    const int stride = gridDim.x * 256;
    const int t0 = blockIdx.x * 256 + threadIdx.x;
    for (int idx = t0; idx < 3 * EH * 33; idx += stride) {
        int d = idx / (EH * 33); int r = idx - d * EH * 33; int u = r / 33; int c = r - u * 33;
        w1t[(d * EH + u) * W1T_STRIDE + c] = ew1[(d * 33 + c) * EH + u];
    }
    for (int idx = t0; idx < 3 * CH * 16; idx += stride) {
        int d = idx / (CH * 16); int r = idx - d * CH * 16; int t = r >> 4; int v = r & 15;
        cw1t[(d * CH + t) * 16 + v] = cw1[(d * 16 + v) * CH + t];
    }
    for (int idx = t0; idx < 3 * NHID * 32; idx += stride) {
        int d = idx / (NHID * 32); int r = idx - d * NHID * 32; int u = r >> 5; int c = r & 31;
        nw1t[(d * NHID + u) * 32 + c] = nw1[(d * 32 + c) * NHID + u];
    }
    for (int idx = t0; idx < 3 * 16 * 32; idx += stride) {
        int d = idx / (16 * 32); int r = idx - d * 16 * 32; int c = r >> 5; int u = r & 31;
        nw2t[(d * 16 + c) * 32 + u] = nw2[(d * 32 + u) * 16 + c];
    }
}

// ---------------- kNN: lane = query, wave = 128-candidate slice, scalar candidate loads ----------------
__device__ __forceinline__ void merge8(u32* a, const u32* bb) {
    // lowest-8 (sorted asc) of two sorted-asc 8-lists: bitonic
    u32 c[8];
#pragma unroll
    for (int t = 0; t < 8; ++t) c[t] = min(a[t], bb[7 - t]);
#define MCAS(x, y) { u32 mn = min(c[x], c[y]); u32 mx = max(c[x], c[y]); c[x] = mn; c[y] = mx; }
    MCAS(0, 4) MCAS(1, 5) MCAS(2, 6) MCAS(3, 7)
    MCAS(0, 2) MCAS(1, 3) MCAS(4, 6) MCAS(5, 7)
    MCAS(0, 1) MCAS(2, 3) MCAS(4, 5) MCAS(6, 7)
#undef MCAS
#pragma unroll
    for (int t = 0; t < 8; ++t) a[t] = c[t];
}

__global__ __launch_bounds__(512) void knn_kernel(
    const float* __restrict__ coords, const int* __restrict__ lengths,
    int* __restrict__ idxbuf)
{
    __shared__ u32 lists[8][64][9];   // pad 9: kills bank conflicts in merge
    const int tid = threadIdx.x;
    const int wv = __builtin_amdgcn_readfirstlane(tid >> 6);  // slice 0..7, wave-uniform
    const int lane = tid & 63;
    const int qblk = blockIdx.x;      // 256 blocks = 16 batches x 16 query-groups
    const int b = qblk >> 4;
    const int i0 = (qblk & 15) << 6;
    const int i = i0 + lane;          // this lane's query
    const int len = lengths[b];
    const float* cb = coords + (size_t)b * SL * 3;
    const float xi = cb[i * 3 + 0], yi = cb[i * 3 + 1], zi = cb[i * 3 + 2];
    const bool mi = i < len;

    u32 lst[8];
#pragma unroll
    for (int t = 0; t < 8; ++t) lst[t] = 0xFFFFFFFFu;

    const int jbase = wv << 7;
#pragma unroll 4
    for (int jj = 0; jj < 128; ++jj) {
        const int j = jbase + jj;
        // wave-uniform index -> scalar loads through sK cache
        const float xj = cb[j * 3 + 0], yj = cb[j * 3 + 1], zj = cb[j * 3 + 2];
        const float dx = xi - xj, dy = yi - yj, dz = zi - zj;
        const float dist = dx * dx + dy * dy + dz * dz;
        const bool pm = mi && (j < len);
        float v = pm ? dist : 1e5f;
        v = (pm && (j - i == 1 || i - j == 1)) ? 0.0f : v;
        v = (j == i) ? -1.0f : v;
        u32 bits = __float_as_uint(v);
        bits ^= (u32)((int)bits >> 31) | 0x80000000u;
        const u32 key = (bits & 0xFFFFFC00u) | (u32)j;
        // predicated insertion into ascending 8-list
#pragma unroll
        for (int p = 7; p >= 1; --p)
            lst[p] = (key < lst[p]) ? ((key < lst[p - 1]) ? lst[p - 1] : key) : lst[p];
        lst[0] = min(key, lst[0]);
    }

#pragma unroll
    for (int t = 0; t < 8; ++t) lists[wv][lane][t] = lst[t];
    __syncthreads();

    // merge tree: 8 lists -> 4 -> 2 -> 1
    if (tid < 256) {
        const int q = tid & 63, p = tid >> 6;
        u32 a[8], bb[8];
#pragma unroll
        for (int t = 0; t < 8; ++t) { a[t] = lists[2 * p][q][t]; bb[t] = lists[2 * p + 1][q][t]; }
        merge8(a, bb);
#pragma unroll
        for (int t = 0; t < 8; ++t) lists[2 * p][q][t] = a[t];
    }
    __syncthreads();
    if (tid < 128) {
        const int q = tid & 63, p = tid >> 6;
        u32 a[8], bb[8];
#pragma unroll
        for (int t = 0; t < 8; ++t) { a[t] = lists[4 * p][q][t]; bb[t] = lists[4 * p + 2][q][t]; }
        merge8(a, bb);
#pragma unroll
        for (int t = 0; t < 8; ++t) lists[4 * p][q][t] = a[t];
    }
    __syncthreads();
    if (tid < 64) {
        const int q = tid;
        u32 a[8], bb[8];
#pragma unroll
        for (int t = 0; t < 8; ++t) { a[t] = lists[0][q][t]; bb[t] = lists[4][q][t]; }
        merge8(a, bb);
        const size_t node = (size_t)b * SL + i0 + q;
        int4 r0 = make_int4((int)(a[0] & 1023u), (int)(a[1] & 1023u), (int)(a[2] & 1023u), (int)(a[3] & 1023u));
        int4 r1 = make_int4((int)(a[4] & 1023u), (int)(a[5] & 1023u), (int)(a[6] & 1023u), (int)(a[7] & 1023u));
        ((int4*)idxbuf)[node * 2 + 0] = r0;
        ((int4*)idxbuf)[node * 2 + 1] = r1;
    }
}

// ---------------- one EGNN layer: thread = (edge, half), cooperative node MLP ----------------
__global__ __launch_bounds__(256, 4) void layer_kernel(
    const int d,
    const float* __restrict__ coordsIn, float* __restrict__ coordsOut,
    const float* __restrict__ featsIn, float* __restrict__ featsOut,
    const int* __restrict__ idxbuf, const int* __restrict__ lengths,
    const float* __restrict__ w1t, const float* __restrict__ g_eb1,
    const float* __restrict__ g_ew2, const float* __restrict__ g_eb2,
    const float* __restrict__ cw1t, const float* __restrict__ g_cb1,
    const float* __restrict__ g_cw2, const float* __restrict__ g_cb2,
    const float* __restrict__ g_lng, const float* __restrict__ g_lnb,
    const float* __restrict__ nw1t, const float* __restrict__ g_nb1,
    const float* __restrict__ nw2t, const float* __restrict__ g_nb2)
{
    const int t = blockIdx.x * 256 + threadIdx.x;   // 0 .. 2*edges-1
    const int h = t & 1;                            // half
    const int e = t >> 1;                           // edge id
    const int n = e >> 3;                           // node id
    const int b = n >> 10;
    const int i = n & (SL - 1);
    const int lnode = threadIdx.x & 15;             // k*2+h within node group
    const int len = lengths[b];
    const int j = idxbuf[e];
    const bool em = (i < len) && (j < len);

    // ---- inputs ----
    float fi[16], fj[16];
    {
        const float4* p = (const float4*)(featsIn + (size_t)n * DIM);
        float4 a = p[0], c2 = p[1], c3 = p[2], c4 = p[3];
        fi[0]=a.x; fi[1]=a.y; fi[2]=a.z; fi[3]=a.w;
        fi[4]=c2.x; fi[5]=c2.y; fi[6]=c2.z; fi[7]=c2.w;
        fi[8]=c3.x; fi[9]=c3.y; fi[10]=c3.z; fi[11]=c3.w;
        fi[12]=c4.x; fi[13]=c4.y; fi[14]=c4.z; fi[15]=c4.w;
    }
    {
        const float4* p = (const float4*)(featsIn + ((size_t)b * SL + j) * DIM);
        float4 a = p[0], c2 = p[1], c3 = p[2], c4 = p[3];
        fj[0]=a.x; fj[1]=a.y; fj[2]=a.z; fj[3]=a.w;
        fj[4]=c2.x; fj[5]=c2.y; fj[6]=c2.z; fj[7]=c2.w;
        fj[8]=c3.x; fj[9]=c3.y; fj[10]=c3.z; fj[11]=c3.w;
        fj[12]=c4.x; fj[13]=c4.y; fj[14]=c4.z; fj[15]=c4.w;
    }
    float ci[3], rel[3];
    {
        const float* cp = coordsIn + (size_t)n * 3;
        const float* cq = coordsIn + ((size_t)b * SL + j) * 3;
        ci[0] = cp[0]; ci[1] = cp[1]; ci[2] = cp[2];
        rel[0] = ci[0] - cq[0]; rel[1] = ci[1] - cq[1]; rel[2] = ci[2] - cq[2];
    }
    const float rd = fmaf(rel[0], rel[0], fmaf(rel[1], rel[1], rel[2] * rel[2]));

    // ---- edge MLP: this half handles hidden units h*33 .. h*33+32 ----
    const float* w1base = w1t + ((size_t)d * EH + h * 33) * W1T_STRIDE;
    const float* eb1r = g_eb1 + d * EH + h * 33;
    const float* w2base = g_ew2 + ((size_t)d * EH + h * 33) * MDIM;
    const float* eb2r = g_eb2 + d * MDIM;
    float macc[16];
#pragma unroll
    for (int v = 0; v < 16; ++v) macc[v] = h ? 0.0f : eb2r[v];
#pragma unroll 3
    for (int uu = 0; uu < 33; ++uu) {
        const float* wr = w1base + uu * W1T_STRIDE;
        float h0 = eb1r[uu], h1 = 0.f, h2 = 0.f, h3 = 0.f;
#pragma unroll
        for (int c = 0; c < 16; c += 4) {
            h0 = fmaf(fi[c + 0], wr[c + 0], h0);
            h1 = fmaf(fi[c + 1], wr[c + 1], h1);
            h2 = fmaf(fi[c + 2], wr[c + 2], h2);
            h3 = fmaf(fi[c + 3], wr[c + 3], h3);
        }
#pragma unroll
        for (int c = 0; c < 16; c += 4) {
            h0 = fmaf(fj[c + 0], wr[16 + c + 0], h0);
            h1 = fmaf(fj[c + 1], wr[16 + c + 1], h1);
            h2 = fmaf(fj[c + 2], wr[16 + c + 2], h2);
            h3 = fmaf(fj[c + 3], wr[16 + c + 3], h3);
        }
        h0 = fmaf(rd, wr[32], h0);
        const float hh = silu_f((h0 + h1) + (h2 + h3));
        const float* w2r = w2base + uu * MDIM;
#pragma unroll
        for (int v = 0; v < 16; ++v) macc[v] = fmaf(hh, w2r[v], macc[v]);
    }
    // combine halves -> both lanes hold full m accumulator
    float mm[16];
#pragma unroll
    for (int v = 0; v < 16; ++v) {
        macc[v] += __shfl_xor(macc[v], 1, 64);
        mm[v] = silu_f(macc[v]);
    }

    // ---- coors MLP: this half handles t = h*32 .. h*32+31 ----
    const float* c1base = cw1t + ((size_t)d * CH + h * 32) * 16;
    const float* cb1r = g_cb1 + d * CH + h * 32;
    const float* cw2r = g_cw2 + d * CH + h * 32;
    float wa = 0.f;
#pragma unroll 4
    for (int tt = 0; tt < 32; ++tt) {
        const float* cr = c1base + tt * 16;
        float a0 = cb1r[tt], a1 = 0.f;
#pragma unroll
        for (int v = 0; v < 16; v += 2) {
            a0 = fmaf(mm[v], cr[v], a0);
            a1 = fmaf(mm[v + 1], cr[v + 1], a1);
        }
        wa = fmaf(silu_f(a0 + a1), cw2r[tt], wa);
    }
    wa += __shfl_xor(wa, 1, 64);
    const float we = em ? (wa + g_cb2[d]) : 0.f;

    // ---- coordinate update: reduce we*rel over 8 edges (halves identical -> xor 2,4,8) ----
    float wr0 = we * rel[0], wr1 = we * rel[1], wr2 = we * rel[2];
#pragma unroll
    for (int s = 2; s < 16; s <<= 1) {
        wr0 += __shfl_xor(wr0, s, 64);
        wr1 += __shfl_xor(wr1, s, 64);
        wr2 += __shfl_xor(wr2, s, 64);
    }
    if (lnode == 0) {
        coordsOut[(size_t)n * 3 + 0] = ci[0] + wr0;
        coordsOut[(size_t)n * 3 + 1] = ci[1] + wr1;
        coordsOut[(size_t)n * 3 + 2] = ci[2] + wr2;
    }

    // ---- m_i: masked sum over 8 edges (halves identical) ----
    float mi_[16];
#pragma unroll
    for (int v = 0; v < 16; ++v) mi_[v] = em ? mm[v] : 0.f;
#pragma unroll
    for (int s = 2; s < 16; s <<= 1) {
#pragma unroll
        for (int v = 0; v < 16; ++v) mi_[v] += __shfl_xor(mi_[v], s, 64);
    }

    // ---- LayerNorm(fi) (redundant per lane, cheap) ----
    float mu = 0.f;
#pragma unroll
    for (int c = 0; c < 16; ++c) mu += fi[c];
    mu *= 0.0625f;
    float var = 0.f;
#pragma unroll
    for (int c = 0; c < 16; ++c) { const float dd = fi[c] - mu; var = fmaf(dd, dd, var); }
    var *= 0.0625f;
    const float rs = rsqrtf(var + LN_EPS);
    const float* lg = g_lng + d * DIM;
    const float* lb = g_lnb + d * DIM;
    float nn[16];
#pragma unroll
    for (int c = 0; c < 16; ++c) nn[c] = fmaf((fi[c] - mu) * rs, lg[c], lb[c]);

    // ---- node MLP hidden: lane lnode computes units lnode and lnode+16 ----
    const float* n1ra = nw1t + ((size_t)d * NHID + lnode) * 32;
    const float* n1rb = nw1t + ((size_t)d * NHID + lnode + 16) * 32;
    float aa = g_nb1[d * NHID + lnode], ab = g_nb1[d * NHID + lnode + 16];
#pragma unroll
    for (int c = 0; c < 16; ++c) {
        aa = fmaf(nn[c], n1ra[c], aa);
        ab = fmaf(nn[c], n1rb[c], ab);
    }
#pragma unroll
    for (int v = 0; v < 16; ++v) {
        aa = fmaf(mi_[v], n1ra[16 + v], aa);
        ab = fmaf(mi_[v], n1rb[16 + v], ab);
    }
    const float nha = silu_f(aa);
    const float nhb = silu_f(ab);

    // ---- node MLP out: lane lnode computes channel lnode via shfl-gather of nh ----
    const float* w2row = nw2t + ((size_t)d * DIM + lnode) * 32;
    float out = g_nb2[d * DIM + lnode];
    const int lbase = (threadIdx.x & 63) & ~15;   // first lane of this node group in wave
#pragma unroll
    for (int u = 0; u < 16; ++u) {
        const float va = __shfl(nha, lbase + u, 64);
        const float vb = __shfl(nhb, lbase + u, 64);
        out = fmaf(va, w2row[u], out);
        out = fmaf(vb, w2row[u + 16], out);
    }
    const float fres = featsIn[(size_t)n * DIM + lnode];
    featsOut[(size_t)n * DIM + lnode] = fres + out;
}

// ---------------- final projection ----------------
__global__ __launch_bounds__(256) void final_kernel(
    const float* __restrict__ feats, const float* __restrict__ fw,
    const float* __restrict__ fb, float* __restrict__ out)
{
    const int nid = blockIdx.x * 256 + threadIdx.x;
    if (nid >= NB * SL) return;
    float f[DIM];
#pragma unroll
    for (int c = 0; c < DIM; ++c) f[c] = feats[nid * DIM + c];
#pragma unroll
    for (int o = 0; o < 3; ++o) {
        float acc = fb[o];
#pragma unroll
        for (int c = 0; c < DIM; ++c) acc = fmaf(f[c], fw[c * 3 + o], acc);
        out[nid * 3 + o] = acc;
    }
}

extern "C" void kernel_launch(void* const* d_in, const int* in_sizes, int n_in,
                              void* d_out, int out_size, void* d_ws, size_t ws_size,
                              hipStream_t stream) {
    const float* coords    = (const float*)d_in[0];
    const int*   residues  = (const int*)d_in[1];
    const int*   lengths   = (const int*)d_in[2];
    const float* token_emb = (const float*)d_in[3];
    const float* pos_emb   = (const float*)d_in[4];
    const float* ew1 = (const float*)d_in[5];
    const float* eb1 = (const float*)d_in[6];
    const float* ew2 = (const float*)d_in[7];
    const float* eb2 = (const float*)d_in[8];
    const float* cw1 = (const float*)d_in[9];
    const float* cb1 = (const float*)d_in[10];
    const float* cw2 = (const float*)d_in[11];
    const float* cb2 = (const float*)d_in[12];
    const float* lng = (const float*)d_in[13];
    const float* lnb = (const float*)d_in[14];
    const float* nw1 = (const float*)d_in[15];
    const float* nb1 = (const float*)d_in[16];
    const float* nw2 = (const float*)d_in[17];
    const float* nb2 = (const float*)d_in[18];
    const float* fw  = (const float*)d_in[19];
    const float* fb  = (const float*)d_in[20];

    float* ws = (float*)d_ws;
    float* coordsA = ws;
    float* coordsB = coordsA + NB * SL * 3;
    float* featsA  = coordsB + NB * SL * 3;
    float* featsB  = featsA + NB * SL * DIM;
    int*   idxbuf  = (int*)(featsB + NB * SL * DIM);
    float* w1t  = (float*)(idxbuf + NB * SL * KNN);
    float* cw1t = w1t + 3 * EH * W1T_STRIDE;
    float* nw1t = cw1t + 3 * CH * 16;
    float* nw2t = nw1t + 3 * NHID * 32;

    pack_kernel<<<32, 256, 0, stream>>>(ew1, cw1, nw1, nw2, w1t, cw1t, nw1t, nw2t);
    init_kernel<<<NB * SL / 256, 256, 0, stream>>>(coords, residues, token_emb, pos_emb, coordsA, featsA);

    float* cIn = coordsA; float* cOut = coordsB;
    float* fIn = featsA;  float* fOut = featsB;
    for (int d = 0; d < 3; ++d) {
        knn_kernel<<<NB * SL / 64, 512, 0, stream>>>(cIn, lengths, idxbuf);
        layer_kernel<<<NB * SL * KNN * 2 / 256, 256, 0, stream>>>(d, cIn, cOut, fIn, fOut, idxbuf, lengths,
            w1t, eb1, ew2, eb2, cw1t, cb1, cw2, cb2, lng, lnb, nw1t, nb1, nw2t, nb2);
        float* t;
        t = cIn; cIn = cOut; cOut = t;
        t = fIn; fIn = fOut; fOut = t;
    }

    final_kernel<<<NB * SL / 256, 256, 0, stream>>>(fIn, fw, fb, (float*)d_out);
}

// Round 4
// 306.147 us; speedup vs baseline: 1.7463x; 1.7463x over previous
//
#include <hip/hip_runtime.h>
#include <math.h>

typedef unsigned long long u64;
typedef unsigned int u32;

#define NB 16
#define SL 1024
#define DIM 16
#define MDIM 16
#define KNN 8
#define EH 66    /* edge hidden */
#define CH 64    /* coors hidden */
#define NHID 32  /* node hidden */
#define LN_EPS 1e-5f
#define W1T_STRIDE 36   /* 33 padded */

__device__ __forceinline__ float silu_f(float x) {
    return x / (1.0f + __expf(-x));
}

// ---------------- init ----------------
__global__ __launch_bounds__(256) void init_kernel(
    const float* __restrict__ coords, const int* __restrict__ residues,
    const float* __restrict__ token_emb, const float* __restrict__ pos_emb,
    float* __restrict__ coordsA, float* __restrict__ featsA)
{
    const int nid = blockIdx.x * 256 + threadIdx.x;
    if (nid >= NB * SL) return;
    const int l = nid & (SL - 1);
    const int r = residues[nid];
#pragma unroll
    for (int c = 0; c < DIM; ++c)
        featsA[nid * DIM + c] = token_emb[r * DIM + c] + pos_emb[l * DIM + c];
#pragma unroll
    for (int c = 0; c < 3; ++c)
        coordsA[nid * 3 + c] = coords[nid * 3 + c];
}

// ---------------- weight transpose/pack ----------------
__global__ __launch_bounds__(256) void pack_kernel(
    const float* __restrict__ ew1, const float* __restrict__ cw1,
    const float* __restrict__ nw1, const float* __restrict__ nw2,
    float* __restrict__ w1t, float* __restrict__ cw1t,
    float* __restrict__ nw1t, float* __restrict__ nw2t)
{
    const int stride = gridDim.x * 256;
    const int t0 = blockIdx.x * 256 + threadIdx.x;
    for (int idx = t0; idx < 3 * EH * 33; idx += stride) {
        int d = idx / (EH * 33); int r = idx - d * EH * 33; int u = r / 33; int c = r - u * 33;
        w1t[(d * EH + u) * W1T_STRIDE + c] = ew1[(d * 33 + c) * EH + u];
    }
    for (int idx = t0; idx < 3 * CH * 16; idx += stride) {
        int d = idx / (CH * 16); int r = idx - d * CH * 16; int t = r >> 4; int v = r & 15;
        cw1t[(d * CH + t) * 16 + v] = cw1[(d * 16 + v) * CH + t];
    }
    for (int idx = t0; idx < 3 * NHID * 32; idx += stride) {
        int d = idx / (NHID * 32); int r = idx - d * NHID * 32; int u = r >> 5; int c = r & 31;
        nw1t[(d * NHID + u) * 32 + c] = nw1[(d * 32 + c) * NHID + u];
    }
    for (int idx = t0; idx < 3 * 16 * 32; idx += stride) {
        int d = idx / (16 * 32); int r = idx - d * 16 * 32; int c = r >> 5; int u = r & 31;
        nw2t[(d * 16 + c) * 32 + u] = nw2[(d * 32 + u) * 16 + c];
    }
}

// ---------------- kNN: candidates staged in LDS, wave-uniform broadcast reads ----------------
__device__ __forceinline__ void merge8(u32* a, const u32* bb) {
    u32 c[8];
#pragma unroll
    for (int t = 0; t < 8; ++t) c[t] = min(a[t], bb[7 - t]);
#define MCAS(x, y) { u32 mn = min(c[x], c[y]); u32 mx = max(c[x], c[y]); c[x] = mn; c[y] = mx; }
    MCAS(0, 4) MCAS(1, 5) MCAS(2, 6) MCAS(3, 7)
    MCAS(0, 2) MCAS(1, 3) MCAS(4, 6) MCAS(5, 7)
    MCAS(0, 1) MCAS(2, 3) MCAS(4, 5) MCAS(6, 7)
#undef MCAS
#pragma unroll
    for (int t = 0; t < 8; ++t) a[t] = c[t];
}

__global__ __launch_bounds__(1024) void knn_kernel(
    const float* __restrict__ coords, const int* __restrict__ lengths,
    int* __restrict__ idxbuf)
{
    __shared__ float s_cand[SL * 3];        // 12 KB
    __shared__ u32 lists[16][64][9];        // 36 KB, pad 9 vs bank conflicts
    const int tid = threadIdx.x;
    const int b = blockIdx.x >> 4;
    const int i0 = (blockIdx.x & 15) << 6;
    const int len = lengths[b];
    const float* cb = coords + (size_t)b * SL * 3;
    for (int idx = tid; idx < SL * 3; idx += 1024) s_cand[idx] = cb[idx];
    __syncthreads();

    const int wv = tid >> 6;     // candidate slice 0..15
    const int lane = tid & 63;   // query within group
    const int i = i0 + lane;
    const bool mi = i < len;
    const float xi = s_cand[i * 3 + 0], yi = s_cand[i * 3 + 1], zi = s_cand[i * 3 + 2];

    u32 lst[8];
#pragma unroll
    for (int t = 0; t < 8; ++t) lst[t] = 0xFFFFFFFFu;

    const int jbase = wv << 6;
#pragma unroll 4
    for (int jj = 0; jj < 64; ++jj) {
        const int j = jbase + jj;
        const float xj = s_cand[j * 3 + 0], yj = s_cand[j * 3 + 1], zj = s_cand[j * 3 + 2];
        const float dx = xi - xj, dy = yi - yj, dz = zi - zj;
        const float dist = dx * dx + dy * dy + dz * dz;
        const bool pm = mi && (j < len);
        float v = pm ? dist : 1e5f;
        v = (pm && (j - i == 1 || i - j == 1)) ? 0.0f : v;
        v = (j == i) ? -1.0f : v;
        u32 bits = __float_as_uint(v);
        bits ^= (u32)((int)bits >> 31) | 0x80000000u;
        const u32 key = (bits & 0xFFFFFC00u) | (u32)j;
#pragma unroll
        for (int p = 7; p >= 1; --p)
            lst[p] = (key < lst[p]) ? ((key < lst[p - 1]) ? lst[p - 1] : key) : lst[p];
        lst[0] = min(key, lst[0]);
    }

#pragma unroll
    for (int t = 0; t < 8; ++t) lists[wv][lane][t] = lst[t];
    __syncthreads();

    if (tid < 512) {
        const int p = tid >> 6, q = tid & 63;
        u32 a[8], bb[8];
#pragma unroll
        for (int t = 0; t < 8; ++t) { a[t] = lists[2 * p][q][t]; bb[t] = lists[2 * p + 1][q][t]; }
        merge8(a, bb);
#pragma unroll
        for (int t = 0; t < 8; ++t) lists[2 * p][q][t] = a[t];
    }
    __syncthreads();
    if (tid < 256) {
        const int p = tid >> 6, q = tid & 63;
        u32 a[8], bb[8];
#pragma unroll
        for (int t = 0; t < 8; ++t) { a[t] = lists[4 * p][q][t]; bb[t] = lists[4 * p + 2][q][t]; }
        merge8(a, bb);
#pragma unroll
        for (int t = 0; t < 8; ++t) lists[4 * p][q][t] = a[t];
    }
    __syncthreads();
    if (tid < 128) {
        const int p = tid >> 6, q = tid & 63;
        u32 a[8], bb[8];
#pragma unroll
        for (int t = 0; t < 8; ++t) { a[t] = lists[8 * p][q][t]; bb[t] = lists[8 * p + 4][q][t]; }
        merge8(a, bb);
#pragma unroll
        for (int t = 0; t < 8; ++t) lists[8 * p][q][t] = a[t];
    }
    __syncthreads();
    if (tid < 64) {
        const int q = tid;
        u32 a[8], bb[8];
#pragma unroll
        for (int t = 0; t < 8; ++t) { a[t] = lists[0][q][t]; bb[t] = lists[8][q][t]; }
        merge8(a, bb);
        const size_t node = (size_t)b * SL + i0 + q;
        int4 r0 = make_int4((int)(a[0] & 1023u), (int)(a[1] & 1023u), (int)(a[2] & 1023u), (int)(a[3] & 1023u));
        int4 r1 = make_int4((int)(a[4] & 1023u), (int)(a[5] & 1023u), (int)(a[6] & 1023u), (int)(a[7] & 1023u));
        ((int4*)idxbuf)[node * 2 + 0] = r0;
        ((int4*)idxbuf)[node * 2 + 1] = r1;
    }
}

// ---------------- EGNN layer: thread=edge, u-range split ACROSS WAVES (wave-uniform h),
// all weights in LDS (uniform-address broadcast reads) ----------------
__global__ __launch_bounds__(256, 4) void layer_kernel(
    const int d,
    const float* __restrict__ coordsIn, float* __restrict__ coordsOut,
    const float* __restrict__ featsIn, float* __restrict__ featsOut,
    const int* __restrict__ idxbuf, const int* __restrict__ lengths,
    const float* __restrict__ w1t, const float* __restrict__ g_eb1,
    const float* __restrict__ g_ew2, const float* __restrict__ g_eb2,
    const float* __restrict__ cw1t, const float* __restrict__ g_cb1,
    const float* __restrict__ g_cw2, const float* __restrict__ g_cb2,
    const float* __restrict__ g_lng, const float* __restrict__ g_lnb,
    const float* __restrict__ nw1t, const float* __restrict__ g_nb1,
    const float* __restrict__ nw2t, const float* __restrict__ g_nb2)
{
    __shared__ float s_w1[EH * 36];                  // 2376
    __shared__ float s_w2e[EH * 16];                 // 1056
    __shared__ float s_cw1[CH * 16];                 // 1024
    __shared__ float s_cw2v[CH];
    __shared__ float s_nw1[NHID * 36];               // padded rows: bank spread
    __shared__ float s_nw2[16 * 36];
    __shared__ float s_eb1[EH], s_eb2[16], s_cb1[CH];
    __shared__ float s_lng[16], s_lnb[16], s_nb1[32], s_nb2[16];
    __shared__ float s_cb2v;
    __shared__ __align__(16) float s_ex[2 * 64 * 20];  // wave-pair exchange, stride 20 (16B-aligned)

    const int tid = threadIdx.x;
    for (int t = tid; t < EH * 36; t += 256) s_w1[t] = w1t[d * EH * 36 + t];
    for (int t = tid; t < EH * 16; t += 256) s_w2e[t] = g_ew2[d * EH * 16 + t];
    for (int t = tid; t < CH * 16; t += 256) s_cw1[t] = cw1t[d * CH * 16 + t];
    for (int t = tid; t < NHID * 32; t += 256) s_nw1[(t >> 5) * 36 + (t & 31)] = nw1t[d * NHID * 32 + t];
    for (int t = tid; t < 16 * 32; t += 256) s_nw2[(t >> 5) * 36 + (t & 31)] = nw2t[d * 16 * 32 + t];
    if (tid < CH) { s_cw2v[tid] = g_cw2[d * CH + tid]; s_cb1[tid] = g_cb1[d * CH + tid]; }
    if (tid < EH) s_eb1[tid] = g_eb1[d * EH + tid];
    if (tid < 16) {
        s_eb2[tid] = g_eb2[d * 16 + tid];
        s_lng[tid] = g_lng[d * 16 + tid];
        s_lnb[tid] = g_lnb[d * 16 + tid];
        s_nb2[tid] = g_nb2[d * 16 + tid];
    }
    if (tid < 32) s_nb1[tid] = g_nb1[d * 32 + tid];
    if (tid == 0) s_cb2v = g_cb2[d];

    const int wvid = tid >> 6;
    const int h = wvid & 1;          // wave-uniform half
    const int p = wvid >> 1;         // wave pair
    const int lane = tid & 63;
    const int e = blockIdx.x * 128 + p * 64 + lane;
    const int n = e >> 3;
    const int b = n >> 10;
    const int i = n & (SL - 1);
    const int k = lane & 7;
    const int len = lengths[b];
    const int j = idxbuf[e];
    const bool em = (i < len) && (j < len);

    // ---- inputs ----
    float fi[16], fj[16];
    {
        const float4* pp = (const float4*)(featsIn + (size_t)n * DIM);
        float4 a = pp[0], c2 = pp[1], c3 = pp[2], c4 = pp[3];
        fi[0]=a.x; fi[1]=a.y; fi[2]=a.z; fi[3]=a.w;
        fi[4]=c2.x; fi[5]=c2.y; fi[6]=c2.z; fi[7]=c2.w;
        fi[8]=c3.x; fi[9]=c3.y; fi[10]=c3.z; fi[11]=c3.w;
        fi[12]=c4.x; fi[13]=c4.y; fi[14]=c4.z; fi[15]=c4.w;
    }
    {
        const float4* pp = (const float4*)(featsIn + ((size_t)b * SL + j) * DIM);
        float4 a = pp[0], c2 = pp[1], c3 = pp[2], c4 = pp[3];
        fj[0]=a.x; fj[1]=a.y; fj[2]=a.z; fj[3]=a.w;
        fj[4]=c2.x; fj[5]=c2.y; fj[6]=c2.z; fj[7]=c2.w;
        fj[8]=c3.x; fj[9]=c3.y; fj[10]=c3.z; fj[11]=c3.w;
        fj[12]=c4.x; fj[13]=c4.y; fj[14]=c4.z; fj[15]=c4.w;
    }
    float ci[3], rel[3];
    {
        const float* cp = coordsIn + (size_t)n * 3;
        const float* cq = coordsIn + ((size_t)b * SL + j) * 3;
        ci[0] = cp[0]; ci[1] = cp[1]; ci[2] = cp[2];
        rel[0] = ci[0] - cq[0]; rel[1] = ci[1] - cq[1]; rel[2] = ci[2] - cq[2];
    }
    const float rd = fmaf(rel[0], rel[0], fmaf(rel[1], rel[1], rel[2] * rel[2]));

    __syncthreads();   // weights staged

    // ---- edge MLP, hidden units [h*33, h*33+33) ----
    const int ub = h * 33;
    float macc[16];
#pragma unroll
    for (int v = 0; v < 16; ++v) macc[v] = h ? 0.0f : s_eb2[v];
#pragma unroll 3
    for (int uu = 0; uu < 33; ++uu) {
        const float* wr = &s_w1[(ub + uu) * 36];
        float h0 = s_eb1[ub + uu], h1 = 0.f, h2 = 0.f, h3 = 0.f;
#pragma unroll
        for (int c = 0; c < 16; c += 4) {
            h0 = fmaf(fi[c + 0], wr[c + 0], h0);
            h1 = fmaf(fi[c + 1], wr[c + 1], h1);
            h2 = fmaf(fi[c + 2], wr[c + 2], h2);
            h3 = fmaf(fi[c + 3], wr[c + 3], h3);
        }
#pragma unroll
        for (int c = 0; c < 16; c += 4) {
            h0 = fmaf(fj[c + 0], wr[16 + c + 0], h0);
            h1 = fmaf(fj[c + 1], wr[16 + c + 1], h1);
            h2 = fmaf(fj[c + 2], wr[16 + c + 2], h2);
            h3 = fmaf(fj[c + 3], wr[16 + c + 3], h3);
        }
        h0 = fmaf(rd, wr[32], h0);
        const float hh = silu_f((h0 + h1) + (h2 + h3));
        const float* w2r = &s_w2e[(ub + uu) * 16];
#pragma unroll
        for (int v = 0; v < 16; ++v) macc[v] = fmaf(hh, w2r[v], macc[v]);
    }

    // ---- combine halves via LDS (stride-20, 16B-aligned) ----
    float4* exq = (float4*)&s_ex[((p << 6) + lane) * 20];
    if (h) {
        exq[0] = make_float4(macc[0], macc[1], macc[2], macc[3]);
        exq[1] = make_float4(macc[4], macc[5], macc[6], macc[7]);
        exq[2] = make_float4(macc[8], macc[9], macc[10], macc[11]);
        exq[3] = make_float4(macc[12], macc[13], macc[14], macc[15]);
    }
    __syncthreads();
    float mm[16];
    if (!h) {
        float4 e0 = exq[0], e1 = exq[1], e2 = exq[2], e3 = exq[3];
        macc[0]+=e0.x; macc[1]+=e0.y; macc[2]+=e0.z; macc[3]+=e0.w;
        macc[4]+=e1.x; macc[5]+=e1.y; macc[6]+=e1.z; macc[7]+=e1.w;
        macc[8]+=e2.x; macc[9]+=e2.y; macc[10]+=e2.z; macc[11]+=e2.w;
        macc[12]+=e3.x; macc[13]+=e3.y; macc[14]+=e3.z; macc[15]+=e3.w;
#pragma unroll
        for (int v = 0; v < 16; ++v) mm[v] = silu_f(macc[v]);
        exq[0] = make_float4(mm[0], mm[1], mm[2], mm[3]);
        exq[1] = make_float4(mm[4], mm[5], mm[6], mm[7]);
        exq[2] = make_float4(mm[8], mm[9], mm[10], mm[11]);
        exq[3] = make_float4(mm[12], mm[13], mm[14], mm[15]);
    }
    __syncthreads();
    if (h) {
        float4 e0 = exq[0], e1 = exq[1], e2 = exq[2], e3 = exq[3];
        mm[0]=e0.x; mm[1]=e0.y; mm[2]=e0.z; mm[3]=e0.w;
        mm[4]=e1.x; mm[5]=e1.y; mm[6]=e1.z; mm[7]=e1.w;
        mm[8]=e2.x; mm[9]=e2.y; mm[10]=e2.z; mm[11]=e2.w;
        mm[12]=e3.x; mm[13]=e3.y; mm[14]=e3.z; mm[15]=e3.w;
    }

    // ---- coors MLP, t-range [h*32, h*32+32) ----
    const int tb = h * 32;
    float wa = 0.f;
#pragma unroll 4
    for (int tt = 0; tt < 32; ++tt) {
        const float* cr = &s_cw1[(tb + tt) * 16];
        float a0 = s_cb1[tb + tt], a1 = 0.f;
#pragma unroll
        for (int v = 0; v < 16; v += 2) {
            a0 = fmaf(mm[v], cr[v], a0);
            a1 = fmaf(mm[v + 1], cr[v + 1], a1);
        }
        wa = fmaf(silu_f(a0 + a1), s_cw2v[tb + tt], wa);
    }
    s_ex[((p << 6) + lane) * 20 + 16 + h] = wa;
    __syncthreads();
    const float wao = s_ex[((p << 6) + lane) * 20 + 17 - h];
    const float we = em ? (wa + wao + s_cb2v) : 0.f;

    // ---- coordinate update: reduce over 8 edges of node ----
    float wr0 = we * rel[0], wr1 = we * rel[1], wr2 = we * rel[2];
#pragma unroll
    for (int s = 1; s < 8; s <<= 1) {
        wr0 += __shfl_xor(wr0, s, 64);
        wr1 += __shfl_xor(wr1, s, 64);
        wr2 += __shfl_xor(wr2, s, 64);
    }
    if (!h && k == 0) {
        coordsOut[(size_t)n * 3 + 0] = ci[0] + wr0;
        coordsOut[(size_t)n * 3 + 1] = ci[1] + wr1;
        coordsOut[(size_t)n * 3 + 2] = ci[2] + wr2;
    }

    // ---- m_i ----
    float mi_[16];
#pragma unroll
    for (int v = 0; v < 16; ++v) mi_[v] = em ? mm[v] : 0.f;
#pragma unroll
    for (int s = 1; s < 8; s <<= 1) {
#pragma unroll
        for (int v = 0; v < 16; ++v) mi_[v] += __shfl_xor(mi_[v], s, 64);
    }

    // ---- LayerNorm ----
    float mu = 0.f;
#pragma unroll
    for (int c = 0; c < 16; ++c) mu += fi[c];
    mu *= 0.0625f;
    float var = 0.f;
#pragma unroll
    for (int c = 0; c < 16; ++c) { const float dd = fi[c] - mu; var = fmaf(dd, dd, var); }
    var *= 0.0625f;
    const float rs = rsqrtf(var + LN_EPS);
    float nn[16];
#pragma unroll
    for (int c = 0; c < 16; ++c) nn[c] = fmaf((fi[c] - mu) * rs, s_lng[c], s_lnb[c]);

    // ---- node MLP hidden: lane k owns units k*4..k*4+3 (fully deduped) ----
    float nh[4];
#pragma unroll
    for (int q = 0; q < 4; ++q) {
        const int u = k * 4 + q;
        const float* nr = &s_nw1[u * 36];
        float a0 = s_nb1[u], a1 = 0.f;
#pragma unroll
        for (int c = 0; c < 16; c += 2) {
            a0 = fmaf(nn[c], nr[c], a0);
            a1 = fmaf(nn[c + 1], nr[c + 1], a1);
        }
#pragma unroll
        for (int v = 0; v < 16; v += 2) {
            a0 = fmaf(mi_[v], nr[16 + v], a0);
            a1 = fmaf(mi_[v + 1], nr[16 + v + 1], a1);
        }
        nh[q] = silu_f(a0 + a1);
    }

    // ---- node MLP out: lane k computes channels 2k, 2k+1 via shfl gather ----
    const int c0 = 2 * k, c1 = 2 * k + 1;
    const float* w2a = &s_nw2[c0 * 36];
    const float* w2b = &s_nw2[c1 * 36];
    float o0 = s_nb2[c0], o1 = s_nb2[c1];
    const int lbase = lane & ~7;
#pragma unroll
    for (int u = 0; u < 32; ++u) {
        const float v = __shfl(nh[u & 3], lbase + (u >> 2), 64);
        o0 = fmaf(v, w2a[u], o0);
        o1 = fmaf(v, w2b[u], o1);
    }
    if (!h) {
        ((float2*)featsOut)[(size_t)n * 8 + k] = make_float2(fi[c0] + o0, fi[c1] + o1);
    }
}

// ---------------- final projection ----------------
__global__ __launch_bounds__(256) void final_kernel(
    const float* __restrict__ feats, const float* __restrict__ fw,
    const float* __restrict__ fb, float* __restrict__ out)
{
    const int nid = blockIdx.x * 256 + threadIdx.x;
    if (nid >= NB * SL) return;
    float f[DIM];
#pragma unroll
    for (int c = 0; c < DIM; ++c) f[c] = feats[nid * DIM + c];
#pragma unroll
    for (int o = 0; o < 3; ++o) {
        float acc = fb[o];
#pragma unroll
        for (int c = 0; c < DIM; ++c) acc = fmaf(f[c], fw[c * 3 + o], acc);
        out[nid * 3 + o] = acc;
    }
}

extern "C" void kernel_launch(void* const* d_in, const int* in_sizes, int n_in,
                              void* d_out, int out_size, void* d_ws, size_t ws_size,
                              hipStream_t stream) {
    const float* coords    = (const float*)d_in[0];
    const int*   residues  = (const int*)d_in[1];
    const int*   lengths   = (const int*)d_in[2];
    const float* token_emb = (const float*)d_in[3];
    const float* pos_emb   = (const float*)d_in[4];
    const float* ew1 = (const float*)d_in[5];
    const float* eb1 = (const float*)d_in[6];
    const float* ew2 = (const float*)d_in[7];
    const float* eb2 = (const float*)d_in[8];
    const float* cw1 = (const float*)d_in[9];
    const float* cb1 = (const float*)d_in[10];
    const float* cw2 = (const float*)d_in[11];
    const float* cb2 = (const float*)d_in[12];
    const float* lng = (const float*)d_in[13];
    const float* lnb = (const float*)d_in[14];
    const float* nw1 = (const float*)d_in[15];
    const float* nb1 = (const float*)d_in[16];
    const float* nw2 = (const float*)d_in[17];
    const float* nb2 = (const float*)d_in[18];
    const float* fw  = (const float*)d_in[19];
    const float* fb  = (const float*)d_in[20];

    float* ws = (float*)d_ws;
    float* coordsA = ws;
    float* coordsB = coordsA + NB * SL * 3;
    float* featsA  = coordsB + NB * SL * 3;
    float* featsB  = featsA + NB * SL * DIM;
    int*   idxbuf  = (int*)(featsB + NB * SL * DIM);
    float* w1t  = (float*)(idxbuf + NB * SL * KNN);
    float* cw1t = w1t + 3 * EH * W1T_STRIDE;
    float* nw1t = cw1t + 3 * CH * 16;
    float* nw2t = nw1t + 3 * NHID * 32;

    pack_kernel<<<32, 256, 0, stream>>>(ew1, cw1, nw1, nw2, w1t, cw1t, nw1t, nw2t);
    init_kernel<<<NB * SL / 256, 256, 0, stream>>>(coords, residues, token_emb, pos_emb, coordsA, featsA);

    float* cIn = coordsA; float* cOut = coordsB;
    float* fIn = featsA;  float* fOut = featsB;
    for (int d = 0; d < 3; ++d) {
        knn_kernel<<<NB * SL / 64, 1024, 0, stream>>>(cIn, lengths, idxbuf);
        layer_kernel<<<NB * SL * KNN / 128, 256, 0, stream>>>(d, cIn, cOut, fIn, fOut, idxbuf, lengths,
            w1t, eb1, ew2, eb2, cw1t, cb1, cw2, cb2, lng, lnb, nw1t, nb1, nw2t, nb2);
        float* t;
        t = cIn; cIn = cOut; cOut = t;
        t = fIn; fIn = fOut; fOut = t;
    }

    final_kernel<<<NB * SL / 256, 256, 0, stream>>>(fIn, fw, fb, (float*)d_out);
}